// Round 6
// baseline (361.014 us; speedup 1.0000x reference)
//
#include <hip/hip_runtime.h>
#include <math.h>

#define TB 8      // batch
#define TT 128    // tokens
#define TD 768    // dim
#define TH 768    // hidden
#define LN_EPS 1e-5f

// 4-K-row FMA body: weight rows in WV[0..3] (4 cols/lane) against
// broadcast activations XQ[b] (float4 = 4 consecutive K values).
#define FMA4(WV, XQ)                                                  \
  {                                                                   \
    _Pragma("unroll") for (int k = 0; k < 4; ++k) {                   \
      _Pragma("unroll") for (int b = 0; b < 8; ++b) {                 \
        const float xv = ((const float*)&XQ[b])[k];                   \
        acc[b][0] = fmaf(xv, (WV)[k].x, acc[b][0]);                   \
        acc[b][1] = fmaf(xv, (WV)[k].y, acc[b][1]);                   \
        acc[b][2] = fmaf(xv, (WV)[k].z, acc[b][2]);                   \
        acc[b][3] = fmaf(xv, (WV)[k].w, acc[b][3]);                   \
      }                                                               \
    }                                                                 \
  }

// ---------------------------------------------------------------------------
// Init: out = x + b2 (residual + FF2 bias). FF2 partials are atomically
// accumulated on top by the fused kernel.
// ---------------------------------------------------------------------------
__global__ __launch_bounds__(256) void init_out_kernel(
    const float* __restrict__ x,    // [B][T][D]
    const float* __restrict__ b2,   // [T][D]
    float* __restrict__ out) {      // [B][T][D]
  const int idx = blockIdx.x * 256 + threadIdx.x;  // float4 index
  const int f = idx * 4;
  const int td = f % (TT * TD);
  const float4 xv = *(const float4*)(x + f);
  const float4 bv = *(const float4*)(b2 + td);     // [t][d] == td within token page
  float4 o;
  o.x = xv.x + bv.x; o.y = xv.y + bv.y;
  o.z = xv.z + bv.z; o.w = xv.w + bv.w;
  *(float4*)(out + f) = o;
}

// ---------------------------------------------------------------------------
// Fused LN + FF1 + GELU + partial-K FF2. Block = (token t, 128-col slice).
// FF1: half-wave owns a 96-row K-chunk of D; lane owns 4 H-cols.
// FF2: this block's h slice (8x128) is multiplied against W2 rows
// [slice*128, slice*128+128) x all 768 D-cols (6 col-blocks of 128);
// half-wave owns 16 of the 128 K-rows; per-wave shfl merge, then
// unsafeAtomicAdd partials into out. No inter-block sync anywhere.
// ---------------------------------------------------------------------------
__global__ __launch_bounds__(256, 3) void fused_ff_kernel(
    const float* __restrict__ x,      // [B][T][D]
    const float* __restrict__ gamma,  // [T][D]
    const float* __restrict__ beta,   // [T][D]
    const float* __restrict__ W1,     // [T][D][H]
    const float* __restrict__ b1,     // [T][H]
    const float* __restrict__ W2,     // [T][H][D]
    float* __restrict__ out) {        // [B][T][D], pre-init x+b2
  __shared__ float st[TB][TD];        // 24 KB xn; first 4 KB reused as h
  __shared__ float red[4][8][128];    // 16 KB FF1 cross-wave partials
  const int tid = threadIdx.x;
  const int w = tid >> 6, lane = tid & 63;
  const int half = lane >> 5, l32 = lane & 31;
  const int hw = w * 2 + half;        // half-wave id 0..7
  const int t = blockIdx.x / 6, slice = blockIdx.x % 6;
  const int cg = l32 * 4;
  const int c = slice * 128 + cg;
  const int r0 = w * 192 + half * 96;

  // ---- fused LN for batch row b = hw ----
  {
    const float* xr = x + ((size_t)hw * TT + t) * TD;
    float4 v[6];
    float s = 0.f, ss = 0.f;
#pragma unroll
    for (int i = 0; i < 6; ++i) {
      v[i] = *(const float4*)(xr + i * 128 + l32 * 4);
      s += v[i].x + v[i].y + v[i].z + v[i].w;
      ss += v[i].x * v[i].x + v[i].y * v[i].y + v[i].z * v[i].z +
            v[i].w * v[i].w;
    }
#pragma unroll
    for (int off = 16; off; off >>= 1) {  // reduce within the 32-lane half
      s  += __shfl_xor(s, off, 64);
      ss += __shfl_xor(ss, off, 64);
    }
    const float mu   = s * (1.f / TD);
    const float var  = ss * (1.f / TD) - mu * mu;
    const float rstd = rsqrtf(var + LN_EPS);
#pragma unroll
    for (int i = 0; i < 6; ++i) {
      const int d = i * 128 + l32 * 4;
      const float4 g  = *(const float4*)(gamma + (size_t)t * TD + d);
      const float4 be = *(const float4*)(beta  + (size_t)t * TD + d);
      float4 o;
      o.x = (v[i].x - mu) * rstd * g.x + be.x;
      o.y = (v[i].y - mu) * rstd * g.y + be.y;
      o.z = (v[i].z - mu) * rstd * g.z + be.z;
      o.w = (v[i].w - mu) * rstd * g.w + be.w;
      *(float4*)&st[hw][d] = o;
    }
  }
  __syncthreads();

  // ---- FF1 K-loop: 96 rows, 4 at a time ----
  float acc[8][4];
#pragma unroll
  for (int b = 0; b < 8; ++b)
#pragma unroll
    for (int j = 0; j < 4; ++j) acc[b][j] = 0.f;

  {
    const float* wp = W1 + ((size_t)t * TD + r0) * TH + c;
#pragma unroll 2
    for (int dd = 0; dd < 96; dd += 4) {
      float4 wv[4];
#pragma unroll
      for (int k = 0; k < 4; ++k) wv[k] = *(const float4*)(wp + k * TH);
      wp += 4 * TH;
      float4 xq[8];
#pragma unroll
      for (int b = 0; b < 8; ++b) xq[b] = *(const float4*)&st[b][r0 + dd];
      FMA4(wv, xq);
    }
  }

#pragma unroll
  for (int b = 0; b < 8; ++b)
#pragma unroll
    for (int j = 0; j < 4; ++j)
      acc[b][j] += __shfl_xor(acc[b][j], 32, 64);
  if (lane < 32) {
#pragma unroll
    for (int b = 0; b < 8; ++b)
      *(float4*)&red[w][b][cg] =
          make_float4(acc[b][0], acc[b][1], acc[b][2], acc[b][3]);
  }
  __syncthreads();   // also: all st reads of FF1 are done after this

  // ---- FF1 epilogue: bias + GELU -> h slice in LDS (aliases st[0][0..1023])
  float* h2 = &st[0][0];  // h2[b*128 + kk], kk = local h col within slice
  {
    const int b = tid >> 5;
    const int colq = (tid & 31) * 4;
    const float4 bias = *(const float4*)(b1 + (size_t)t * TH + slice * 128 + colq);
    float4 o;
    float* po = (float*)&o;
    const float* pb = (const float*)&bias;
#pragma unroll
    for (int k = 0; k < 4; ++k) {
      float vv = red[0][b][colq + k] + red[1][b][colq + k] +
                 red[2][b][colq + k] + red[3][b][colq + k] + pb[k];
      po[k] = 0.5f * vv * (1.f + erff(vv * 0.7071067811865476f));
    }
    *(float4*)&h2[b * 128 + colq] = o;
  }
  __syncthreads();

  // ---- FF2 partial-K: h2[8][128] @ W2[slice*128 .. +128)[all 768 cols] ----
  // Half-wave hw owns K-rows [hw*16, hw*16+16). 6 col-blocks of 128.
  const float* w2base =
      W2 + ((size_t)t * TH + slice * 128 + hw * 16) * TD + cg;
  float* outt = out + (size_t)t * TD;  // [b] stride TT*TD
#pragma unroll 1
  for (int cb = 0; cb < 6; ++cb) {
#pragma unroll
    for (int b = 0; b < 8; ++b)
#pragma unroll
      for (int j = 0; j < 4; ++j) acc[b][j] = 0.f;

    const float* wp = w2base + cb * 128;
#pragma unroll
    for (int rg = 0; rg < 4; ++rg) {  // 16 rows, 4 at a time
      float4 wv[4];
#pragma unroll
      for (int k = 0; k < 4; ++k) wv[k] = *(const float4*)(wp + (rg * 4 + k) * TD);
      float4 xq[8];
#pragma unroll
      for (int b = 0; b < 8; ++b)
        xq[b] = *(const float4*)&h2[b * 128 + hw * 16 + rg * 4];
      FMA4(wv, xq);
    }

#pragma unroll
    for (int b = 0; b < 8; ++b)
#pragma unroll
      for (int j = 0; j < 4; ++j)
        acc[b][j] += __shfl_xor(acc[b][j], 32, 64);

    if (lane < 32) {
      const int d = cb * 128 + cg;
#pragma unroll
      for (int b = 0; b < 8; ++b) {
        float* po = outt + (size_t)b * (TT * TD) + d;
#pragma unroll
        for (int j = 0; j < 4; ++j) unsafeAtomicAdd(po + j, acc[b][j]);
      }
    }
  }
}

extern "C" void kernel_launch(void* const* d_in, const int* in_sizes, int n_in,
                              void* d_out, int out_size, void* d_ws, size_t ws_size,
                              hipStream_t stream) {
  const float* x     = (const float*)d_in[0];
  const float* gamma = (const float*)d_in[1];
  const float* beta  = (const float*)d_in[2];
  const float* W1    = (const float*)d_in[3];
  const float* b1    = (const float*)d_in[4];
  const float* W2    = (const float*)d_in[5];
  const float* b2    = (const float*)d_in[6];
  float* out = (float*)d_out;

  init_out_kernel<<<(TB * TT * TD) / (256 * 4), 256, 0, stream>>>(x, b2, out);
  fused_ff_kernel<<<TT * 6, 256, 0, stream>>>(x, gamma, beta, W1, b1, W2, out);
}

// Round 7
// 245.904 us; speedup vs baseline: 1.4681x; 1.4681x over previous
//
#include <hip/hip_runtime.h>
#include <math.h>

#define TB 8      // batch
#define TT 128    // tokens
#define TD 768    // dim
#define TH 768    // hidden
#define LN_EPS 1e-5f

// ===========================================================================
// PRIMARY PATH: contiguous-stream partial-K design (needs ~41 MB ws).
//   ln_kernel : x -> xn[T][B][D]
//   gemm<0>   : partial1[t][chunk] = xn[t][:,chunk] @ W1[t][chunk,:]   (raw)
//   gemm<1>   : h = gelu(sum_c partial1 + b1);  partial2[t][chunk] = ...
//   k4        : out = sum_c partial2 + b2 + x
// Every weight byte is read exactly once, as part of a per-block contiguous
// 384 KB stream (16 tiles x 24 KB, double-buffered through LDS).
// ===========================================================================

__global__ __launch_bounds__(256) void ln_kernel(
    const float* __restrict__ x,      // [B][T][D]
    const float* __restrict__ gamma,  // [T][D]
    const float* __restrict__ beta,   // [T][D]
    float* __restrict__ xn) {         // [T][B][D]
  const int w = threadIdx.x >> 6, lane = threadIdx.x & 63;
  const int r = blockIdx.x * 4 + w;   // r = b*T + t
  const int t = r & (TT - 1);
  const int b = r >> 7;
  const float* xr = x + (size_t)r * TD;

  float v[12];
  float s = 0.f, ss = 0.f;
#pragma unroll
  for (int i = 0; i < 3; ++i) {
    float4 f = *(const float4*)(xr + i * 256 + lane * 4);
    v[i * 4 + 0] = f.x; v[i * 4 + 1] = f.y;
    v[i * 4 + 2] = f.z; v[i * 4 + 3] = f.w;
    s += f.x + f.y + f.z + f.w;
    ss += f.x * f.x + f.y * f.y + f.z * f.z + f.w * f.w;
  }
#pragma unroll
  for (int off = 32; off; off >>= 1) {
    s  += __shfl_down(s, off, 64);
    ss += __shfl_down(ss, off, 64);
  }
  s = __shfl(s, 0, 64); ss = __shfl(ss, 0, 64);
  const float mu   = s * (1.f / TD);
  const float var  = ss * (1.f / TD) - mu * mu;
  const float rstd = rsqrtf(var + LN_EPS);

#pragma unroll
  for (int i = 0; i < 3; ++i) {
    const int d = i * 256 + lane * 4;
    float4 g  = *(const float4*)(gamma + (size_t)t * TD + d);
    float4 be = *(const float4*)(beta  + (size_t)t * TD + d);
    float4 o;
    o.x = (v[i * 4 + 0] - mu) * rstd * g.x + be.x;
    o.y = (v[i * 4 + 1] - mu) * rstd * g.y + be.y;
    o.z = (v[i * 4 + 2] - mu) * rstd * g.z + be.z;
    o.w = (v[i * 4 + 3] - mu) * rstd * g.w + be.w;
    *(float4*)(xn + ((size_t)t * TB + b) * TD + d) = o;
  }
}

// Block = (t, chunk). Streams 128 contiguous weight rows x 768 cols (384 KB)
// through LDS in 16 double-buffered 8-row tiles. Thread owns 3 cols
// (stride-3 LDS reads: 2-way bank alias = free). acc[8 batches][3 cols].
// IS_G2=0: act = xn slice (raw partials out). IS_G2=1: act = gelu(sum
// partial1 + b1) (prologue reduce), partials2 out.
template <int IS_G2>
__global__ __launch_bounds__(256, 3) void gemm_kernel(
    const float* __restrict__ act_src,  // G1: xn[T][B][D]; G2: partial1
    const float* __restrict__ W,        // [T][768][768]
    const float* __restrict__ bias,     // G2 only: b1[T][H]
    float* __restrict__ pout) {         // partial[T][6][TB][768]
  __shared__ float wt[2][8][768];       // 48 KB weight tiles
  __shared__ float as[TB][128];         // 4 KB activation slice
  const int tid = threadIdx.x;
  const int t = blockIdx.x / 6, chunk = blockIdx.x % 6;
  const int c0 = tid * 3;               // 3 owned cols

  const float* wbase = W + ((size_t)t * 768 + chunk * 128) * 768;

  // ---- issue tile-0 loads immediately (weight stream starts at cycle ~0)
  float4 rstage[6];
#pragma unroll
  for (int k = 0; k < 6; ++k)
    rstage[k] = *(const float4*)(wbase + (tid + k * 256) * 4);

  // ---- activation prologue ----
  {
    const int b = tid >> 5, q = (tid & 31) * 4;
    if (IS_G2) {
      // reduce 6 FF1 partials + bias, GELU -> as[b][q..q+4)
      float4 sum;
      {
        const float* p = act_src + ((size_t)(t * 6 + 0) * TB + b) * 768 +
                         chunk * 128 + q;
        sum = *(const float4*)p;
      }
#pragma unroll
      for (int c = 1; c < 6; ++c) {
        const float* p = act_src + ((size_t)(t * 6 + c) * TB + b) * 768 +
                         chunk * 128 + q;
        const float4 v = *(const float4*)p;
        sum.x += v.x; sum.y += v.y; sum.z += v.z; sum.w += v.w;
      }
      const float4 bv = *(const float4*)(bias + (size_t)t * TH + chunk * 128 + q);
      float4 o;
      o.x = sum.x + bv.x; o.y = sum.y + bv.y;
      o.z = sum.z + bv.z; o.w = sum.w + bv.w;
      float* po = (float*)&o;
#pragma unroll
      for (int k = 0; k < 4; ++k)
        po[k] = 0.5f * po[k] * (1.f + erff(po[k] * 0.7071067811865476f));
      *(float4*)&as[b][q] = o;
    } else {
      // copy xn[t][b][chunk*128 + q .. +4)
      *(float4*)&as[b][q] =
          *(const float4*)(act_src + ((size_t)t * TB + b) * TD + chunk * 128 + q);
    }
  }

  // commit tile 0 to LDS
#pragma unroll
  for (int k = 0; k < 6; ++k)
    *(float4*)&wt[0][0][(tid + k * 256) * 4] = rstage[k];
  __syncthreads();

  float acc[8][3];
#pragma unroll
  for (int b = 0; b < 8; ++b)
#pragma unroll
    for (int j = 0; j < 3; ++j) acc[b][j] = 0.f;

#pragma unroll 1
  for (int tile = 0; tile < 16; ++tile) {
    const int buf = tile & 1;
    if (tile < 15) {  // issue next-tile loads (overlap compute)
      const float* src = wbase + (size_t)(tile + 1) * 8 * 768;
#pragma unroll
      for (int k = 0; k < 6; ++k)
        rstage[k] = *(const float4*)(src + (tid + k * 256) * 4);
    }
    // compute this tile: 8 rows x 3 cols x 8 batches
    float wr[8][3];
#pragma unroll
    for (int r = 0; r < 8; ++r)
#pragma unroll
      for (int j = 0; j < 3; ++j) wr[r][j] = wt[buf][r][c0 + j];
#pragma unroll
    for (int b = 0; b < 8; ++b) {
      float xa[8];
      *(float4*)&xa[0] = *(const float4*)&as[b][tile * 8];
      *(float4*)&xa[4] = *(const float4*)&as[b][tile * 8 + 4];
#pragma unroll
      for (int r = 0; r < 8; ++r) {
        acc[b][0] = fmaf(xa[r], wr[r][0], acc[b][0]);
        acc[b][1] = fmaf(xa[r], wr[r][1], acc[b][1]);
        acc[b][2] = fmaf(xa[r], wr[r][2], acc[b][2]);
      }
    }
    if (tile < 15) {
#pragma unroll
      for (int k = 0; k < 6; ++k)
        *(float4*)&wt[buf ^ 1][0][(tid + k * 256) * 4] = rstage[k];
    }
    __syncthreads();
  }

  // ---- epilogue: stage acc through LDS, then coalesced float4 stores ----
  float* ob = &wt[0][0][0];  // reuse as [8][768]
#pragma unroll
  for (int b = 0; b < 8; ++b)
#pragma unroll
    for (int j = 0; j < 3; ++j) ob[b * 768 + c0 + j] = acc[b][j];
  __syncthreads();
  {
    float* dst = pout + (size_t)(t * 6 + chunk) * TB * 768;
#pragma unroll
    for (int k = 0; k < 6; ++k)
      *(float4*)(dst + (tid + k * 256) * 4) =
          *(const float4*)(ob + (tid + k * 256) * 4);
  }
}

__global__ __launch_bounds__(256) void k4_kernel(
    const float* __restrict__ p2,   // [T][6][TB][TD]
    const float* __restrict__ b2,   // [T][D]
    const float* __restrict__ x,    // [B][T][D]
    float* __restrict__ out) {      // [B][T][D]
  const int f = (blockIdx.x * 256 + threadIdx.x) * 4;
  const int b = f / (TT * TD);
  const int r = f % (TT * TD);      // t*TD + d
  const int t = r / TD, d = r % TD;
  float4 acc = *(const float4*)(b2 + r);
  const float4 xv = *(const float4*)(x + f);
  acc.x += xv.x; acc.y += xv.y; acc.z += xv.z; acc.w += xv.w;
#pragma unroll
  for (int c = 0; c < 6; ++c) {
    const float4 v =
        *(const float4*)(p2 + ((size_t)(t * 6 + c) * TB + b) * TD + d);
    acc.x += v.x; acc.y += v.y; acc.z += v.z; acc.w += v.w;
  }
  *(float4*)(out + f) = acc;
}

// ===========================================================================
// FALLBACK PATH (ws < 41 MB): round-3 two-kernel structure (115.6 us).
// ===========================================================================
#define BODY4(WV, ROW)                                                \
  {                                                                   \
    float4 xq[8];                                                     \
    _Pragma("unroll") for (int b = 0; b < 8; ++b)                     \
        xq[b] = *(const float4*)&st[b][(ROW)];                        \
    _Pragma("unroll") for (int k = 0; k < 4; ++k) {                   \
      _Pragma("unroll") for (int b = 0; b < 8; ++b) {                 \
        const float xv = ((const float*)&xq[b])[k];                   \
        acc[b][0] = fmaf(xv, (WV)[k].x, acc[b][0]);                   \
        acc[b][1] = fmaf(xv, (WV)[k].y, acc[b][1]);                   \
        acc[b][2] = fmaf(xv, (WV)[k].z, acc[b][2]);                   \
        acc[b][3] = fmaf(xv, (WV)[k].w, acc[b][3]);                   \
      }                                                               \
    }                                                                 \
  }

__global__ __launch_bounds__(256) void ff1_fb(
    const float* __restrict__ x, const float* __restrict__ gamma,
    const float* __restrict__ beta, const float* __restrict__ W1,
    const float* __restrict__ b1, float* __restrict__ hbuf) {
  __shared__ float st[TB][TD];
  __shared__ float red[4][8][128];
  const int tid = threadIdx.x;
  const int w = tid >> 6, lane = tid & 63;
  const int half = lane >> 5, l32 = lane & 31;
  const int t = blockIdx.x / 6, slice = blockIdx.x % 6;
  const int cg = l32 * 4, c = slice * 128 + cg, r0 = w * 192 + half * 96;
  {
    const int b = w * 2 + half;
    const float* xr = x + ((size_t)b * TT + t) * TD;
    float4 v[6]; float s = 0.f, ss = 0.f;
#pragma unroll
    for (int i = 0; i < 6; ++i) {
      v[i] = *(const float4*)(xr + i * 128 + l32 * 4);
      s += v[i].x + v[i].y + v[i].z + v[i].w;
      ss += v[i].x * v[i].x + v[i].y * v[i].y + v[i].z * v[i].z + v[i].w * v[i].w;
    }
#pragma unroll
    for (int off = 16; off; off >>= 1) { s += __shfl_xor(s, off, 64); ss += __shfl_xor(ss, off, 64); }
    const float mu = s * (1.f / TD), var = ss * (1.f / TD) - mu * mu;
    const float rstd = rsqrtf(var + LN_EPS);
#pragma unroll
    for (int i = 0; i < 6; ++i) {
      const int d = i * 128 + l32 * 4;
      const float4 g = *(const float4*)(gamma + (size_t)t * TD + d);
      const float4 be = *(const float4*)(beta + (size_t)t * TD + d);
      float4 o;
      o.x = (v[i].x - mu) * rstd * g.x + be.x; o.y = (v[i].y - mu) * rstd * g.y + be.y;
      o.z = (v[i].z - mu) * rstd * g.z + be.z; o.w = (v[i].w - mu) * rstd * g.w + be.w;
      *(float4*)&st[b][d] = o;
    }
  }
  __syncthreads();
  float acc[8][4];
#pragma unroll
  for (int b = 0; b < 8; ++b)
#pragma unroll
    for (int j = 0; j < 4; ++j) acc[b][j] = 0.f;
  {
    const float* wp = W1 + ((size_t)t * TD + r0) * TH + c;
#pragma unroll 2
    for (int dd = 0; dd < 96; dd += 4) {
      float4 wv[4];
#pragma unroll
      for (int k = 0; k < 4; ++k) wv[k] = *(const float4*)(wp + k * TH);
      wp += 4 * TH;
      BODY4(wv, r0 + dd);
    }
  }
#pragma unroll
  for (int b = 0; b < 8; ++b)
#pragma unroll
    for (int j = 0; j < 4; ++j) acc[b][j] += __shfl_xor(acc[b][j], 32, 64);
  if (lane < 32) {
#pragma unroll
    for (int b = 0; b < 8; ++b)
      *(float4*)&red[w][b][cg] = make_float4(acc[b][0], acc[b][1], acc[b][2], acc[b][3]);
  }
  __syncthreads();
  {
    const int b = tid >> 5, colq = (tid & 31) * 4, cc = slice * 128 + colq;
    const float4 bias = *(const float4*)(b1 + (size_t)t * TH + cc);
    float4 o; float* po = (float*)&o; const float* pb = (const float*)&bias;
#pragma unroll
    for (int k = 0; k < 4; ++k) {
      float vv = red[0][b][colq + k] + red[1][b][colq + k] + red[2][b][colq + k] +
                 red[3][b][colq + k] + pb[k];
      po[k] = 0.5f * vv * (1.f + erff(vv * 0.7071067811865476f));
    }
    *(float4*)(hbuf + ((size_t)t * TB + b) * TH + cc) = o;
  }
}

__global__ __launch_bounds__(256) void ff2_fb(
    const float* __restrict__ hbuf, const float* __restrict__ W2,
    const float* __restrict__ b2, const float* __restrict__ x,
    float* __restrict__ out) {
  __shared__ float st[TB][TH];
  __shared__ float red[4][8][128];
  const int tid = threadIdx.x;
  const int w = tid >> 6, lane = tid & 63;
  const int half = lane >> 5, l32 = lane & 31;
  const int t = blockIdx.x / 6, slice = blockIdx.x % 6;
  const int cg = l32 * 4, c = slice * 128 + cg, r0 = w * 192 + half * 96;
  {
    const float4* src = (const float4*)(hbuf + (size_t)t * TB * TH);
    float4* dst = (float4*)&st[0][0];
#pragma unroll
    for (int i = 0; i < 6; ++i) dst[tid + i * 256] = src[tid + i * 256];
  }
  __syncthreads();
  float acc[8][4];
#pragma unroll
  for (int b = 0; b < 8; ++b)
#pragma unroll
    for (int j = 0; j < 4; ++j) acc[b][j] = 0.f;
  {
    const float* wp = W2 + ((size_t)t * TH + r0) * TD + c;
#pragma unroll 2
    for (int dd = 0; dd < 96; dd += 4) {
      float4 wv[4];
#pragma unroll
      for (int k = 0; k < 4; ++k) wv[k] = *(const float4*)(wp + k * TD);
      wp += 4 * TD;
      BODY4(wv, r0 + dd);
    }
  }
#pragma unroll
  for (int b = 0; b < 8; ++b)
#pragma unroll
    for (int j = 0; j < 4; ++j) acc[b][j] += __shfl_xor(acc[b][j], 32, 64);
  if (lane < 32) {
#pragma unroll
    for (int b = 0; b < 8; ++b)
      *(float4*)&red[w][b][cg] = make_float4(acc[b][0], acc[b][1], acc[b][2], acc[b][3]);
  }
  __syncthreads();
  {
    const int b = tid >> 5, colq = (tid & 31) * 4, cc = slice * 128 + colq;
    const size_t off = ((size_t)b * TT + t) * TD + cc;
    const float4 bias = *(const float4*)(b2 + (size_t)t * TD + cc);
    const float4 xres = *(const float4*)(x + off);
    float4 o; float* po = (float*)&o;
    const float* pb = (const float*)&bias; const float* px = (const float*)&xres;
#pragma unroll
    for (int k = 0; k < 4; ++k)
      po[k] = red[0][b][colq + k] + red[1][b][colq + k] + red[2][b][colq + k] +
              red[3][b][colq + k] + pb[k] + px[k];
    *(float4*)(out + off) = o;
  }
}

extern "C" void kernel_launch(void* const* d_in, const int* in_sizes, int n_in,
                              void* d_out, int out_size, void* d_ws, size_t ws_size,
                              hipStream_t stream) {
  const float* x     = (const float*)d_in[0];
  const float* gamma = (const float*)d_in[1];
  const float* beta  = (const float*)d_in[2];
  const float* W1    = (const float*)d_in[3];
  const float* b1    = (const float*)d_in[4];
  const float* W2    = (const float*)d_in[5];
  const float* b2    = (const float*)d_in[6];
  float* out = (float*)d_out;

  const size_t n_xn = (size_t)TT * TB * TD;        // 786432
  const size_t n_p  = (size_t)TT * 6 * TB * 768;   // 4718592
  const size_t need = (n_xn + 2 * n_p) * sizeof(float);  // ~40.9 MB

  if (ws_size >= need) {
    float* xn = (float*)d_ws;
    float* p1 = xn + n_xn;
    float* p2 = p1 + n_p;
    ln_kernel<<<256, 256, 0, stream>>>(x, gamma, beta, xn);
    gemm_kernel<0><<<TT * 6, 256, 0, stream>>>(xn, W1, nullptr, p1);
    gemm_kernel<1><<<TT * 6, 256, 0, stream>>>(p1, W2, b1, p2);
    k4_kernel<<<(TB * TT * TD) / (256 * 4), 256, 0, stream>>>(p2, b2, x, out);
  } else {
    float* hbuf = (float*)d_ws;  // 3 MB
    ff1_fb<<<TT * 6, 256, 0, stream>>>(x, gamma, beta, W1, b1, hbuf);
    ff2_fb<<<TT * 6, 256, 0, stream>>>(hbuf, W2, b2, x, out);
  }
}

// Round 8
// 116.531 us; speedup vs baseline: 3.0980x; 2.1102x over previous
//
#include <hip/hip_runtime.h>
#include <math.h>

#define TB 8      // batch
#define TT 128    // tokens
#define TD 768    // dim
#define TH 768    // hidden
#define LN_EPS 1e-5f

// 4-K-row FMA body: weight rows in WV[0..3] (4 cols/lane) against
// LDS-broadcast activations st[b][ROW..ROW+3].
#define BODY4(WV, ROW)                                                \
  {                                                                   \
    float4 xq[8];                                                     \
    _Pragma("unroll") for (int b = 0; b < 8; ++b)                     \
        xq[b] = *(const float4*)&st[b][(ROW)];                        \
    _Pragma("unroll") for (int k = 0; k < 4; ++k) {                   \
      _Pragma("unroll") for (int b = 0; b < 8; ++b) {                 \
        const float xv = ((const float*)&xq[b])[k];                   \
        acc[b][0] = fmaf(xv, (WV)[k].x, acc[b][0]);                   \
        acc[b][1] = fmaf(xv, (WV)[k].y, acc[b][1]);                   \
        acc[b][2] = fmaf(xv, (WV)[k].z, acc[b][2]);                   \
        acc[b][3] = fmaf(xv, (WV)[k].w, acc[b][3]);                   \
      }                                                               \
    }                                                                 \
  }

// ---------------------------------------------------------------------------
// FF1 with fused LayerNorm. Block = (token t, 128-col slice of H), 256 thr.
// Half-wave owns a 96-row K-chunk (8-way K split); lane owns 4 cols (float4
// weight loads, 16 B/lane). First 8 weight rows prefetched into registers
// BEFORE the LN compute so the weight stream starts immediately.
// ---------------------------------------------------------------------------
__global__ __launch_bounds__(256) void ff1_kernel(
    const float* __restrict__ x,      // [B][T][D]
    const float* __restrict__ gamma,  // [T][D]
    const float* __restrict__ beta,   // [T][D]
    const float* __restrict__ W1,     // [T][D][H]
    const float* __restrict__ b1,     // [T][H]
    float* __restrict__ hbuf) {       // [T][B][H]
  __shared__ float st[TB][TD];        // 24 KB normalized activations
  __shared__ float red[4][8][128];    // 16 KB partial sums
  const int tid = threadIdx.x;
  const int w = tid >> 6, lane = tid & 63;
  const int half = lane >> 5, l32 = lane & 31;
  const int t = blockIdx.x / 6, slice = blockIdx.x % 6;
  const int cg = l32 * 4;
  const int c = slice * 128 + cg;
  const int r0 = w * 192 + half * 96;

  const float* wp1 = W1 + ((size_t)t * TD + r0) * TH + c;

  // ---- LN x-loads first (needed soonest), then weight prefetch ----
  const int bb = w * 2 + half;
  const float* xr = x + ((size_t)bb * TT + t) * TD;
  float4 v[6];
#pragma unroll
  for (int i = 0; i < 6; ++i)
    v[i] = *(const float4*)(xr + i * 128 + l32 * 4);

  float4 pA[4], pB[4];
#pragma unroll
  for (int k = 0; k < 4; ++k) pA[k] = *(const float4*)(wp1 + k * TH);
#pragma unroll
  for (int k = 0; k < 4; ++k) pB[k] = *(const float4*)(wp1 + (4 + k) * TH);

  {  // ---- fused LN for batch row bb ----
    float s = 0.f, ss = 0.f;
#pragma unroll
    for (int i = 0; i < 6; ++i) {
      s += v[i].x + v[i].y + v[i].z + v[i].w;
      ss += v[i].x * v[i].x + v[i].y * v[i].y + v[i].z * v[i].z +
            v[i].w * v[i].w;
    }
#pragma unroll
    for (int off = 16; off; off >>= 1) {  // reduce within the 32-lane half
      s  += __shfl_xor(s, off, 64);
      ss += __shfl_xor(ss, off, 64);
    }
    const float mu   = s * (1.f / TD);
    const float var  = ss * (1.f / TD) - mu * mu;
    const float rstd = rsqrtf(var + LN_EPS);
#pragma unroll
    for (int i = 0; i < 6; ++i) {
      const int d = i * 128 + l32 * 4;
      const float4 g  = *(const float4*)(gamma + (size_t)t * TD + d);
      const float4 be = *(const float4*)(beta  + (size_t)t * TD + d);
      float4 o;
      o.x = (v[i].x - mu) * rstd * g.x + be.x;
      o.y = (v[i].y - mu) * rstd * g.y + be.y;
      o.z = (v[i].z - mu) * rstd * g.z + be.z;
      o.w = (v[i].w - mu) * rstd * g.w + be.w;
      *(float4*)&st[bb][d] = o;
    }
  }
  __syncthreads();

  float acc[8][4];
#pragma unroll
  for (int b = 0; b < 8; ++b)
#pragma unroll
    for (int j = 0; j < 4; ++j) acc[b][j] = 0.f;

  BODY4(pA, r0);
  BODY4(pB, r0 + 4);
  {
    const float* wp = wp1 + 8 * TH;
#pragma unroll 2
    for (int dd = 8; dd < 96; dd += 4) {
      float4 wv[4];
#pragma unroll
      for (int k = 0; k < 4; ++k) wv[k] = *(const float4*)(wp + k * TH);
      wp += 4 * TH;
      BODY4(wv, r0 + dd);
    }
  }

#pragma unroll
  for (int b = 0; b < 8; ++b)
#pragma unroll
    for (int j = 0; j < 4; ++j)
      acc[b][j] += __shfl_xor(acc[b][j], 32, 64);
  if (lane < 32) {
#pragma unroll
    for (int b = 0; b < 8; ++b)
      *(float4*)&red[w][b][cg] =
          make_float4(acc[b][0], acc[b][1], acc[b][2], acc[b][3]);
  }
  __syncthreads();

  {  // epilogue: bias + GELU, thread -> (batch row, 4-col group)
    const int b = tid >> 5;
    const int colq = (tid & 31) * 4;
    const int cc = slice * 128 + colq;
    const float4 bias = *(const float4*)(b1 + (size_t)t * TH + cc);
    float4 o;
    float* po = (float*)&o;
    const float* pb = (const float*)&bias;
#pragma unroll
    for (int k = 0; k < 4; ++k) {
      float vv = red[0][b][colq + k] + red[1][b][colq + k] +
                 red[2][b][colq + k] + red[3][b][colq + k] + pb[k];
      po[k] = 0.5f * vv * (1.f + erff(vv * 0.7071067811865476f));
    }
    *(float4*)(hbuf + ((size_t)t * TB + b) * TH + cc) = o;
  }
}

// ---------------------------------------------------------------------------
// FF2: out = h @ W2 + b2 + x. Same structure; W2 prefetch issued before the
// hbuf->LDS stage so the weight stream starts immediately.
// ---------------------------------------------------------------------------
__global__ __launch_bounds__(256) void ff2_kernel(
    const float* __restrict__ hbuf, // [T][B][H]
    const float* __restrict__ W2,   // [T][H][D]
    const float* __restrict__ b2,   // [T][D]
    const float* __restrict__ x,    // [B][T][D]
    float* __restrict__ out) {      // [B][T][D]
  __shared__ float st[TB][TH];
  __shared__ float red[4][8][128];
  const int tid = threadIdx.x;
  const int w = tid >> 6, lane = tid & 63;
  const int half = lane >> 5, l32 = lane & 31;
  const int t = blockIdx.x / 6, slice = blockIdx.x % 6;
  const int cg = l32 * 4;
  const int c = slice * 128 + cg;
  const int r0 = w * 192 + half * 96;

  const float* wp2 = W2 + ((size_t)t * TH + r0) * TD + c;
  float4 pA[4], pB[4];
#pragma unroll
  for (int k = 0; k < 4; ++k) pA[k] = *(const float4*)(wp2 + k * TD);
#pragma unroll
  for (int k = 0; k < 4; ++k) pB[k] = *(const float4*)(wp2 + (4 + k) * TD);

  {  // contiguous stage: hbuf[t] is [8][768] = exactly st's layout
    const float4* src = (const float4*)(hbuf + (size_t)t * TB * TH);
    float4* dst = (float4*)&st[0][0];
#pragma unroll
    for (int i = 0; i < 6; ++i) dst[tid + i * 256] = src[tid + i * 256];
  }
  __syncthreads();

  float acc[8][4];
#pragma unroll
  for (int b = 0; b < 8; ++b)
#pragma unroll
    for (int j = 0; j < 4; ++j) acc[b][j] = 0.f;

  BODY4(pA, r0);
  BODY4(pB, r0 + 4);
  {
    const float* wp = wp2 + 8 * TD;
#pragma unroll 2
    for (int dd = 8; dd < 96; dd += 4) {
      float4 wv[4];
#pragma unroll
      for (int k = 0; k < 4; ++k) wv[k] = *(const float4*)(wp + k * TD);
      wp += 4 * TD;
      BODY4(wv, r0 + dd);
    }
  }

#pragma unroll
  for (int b = 0; b < 8; ++b)
#pragma unroll
    for (int j = 0; j < 4; ++j)
      acc[b][j] += __shfl_xor(acc[b][j], 32, 64);
  if (lane < 32) {
#pragma unroll
    for (int b = 0; b < 8; ++b)
      *(float4*)&red[w][b][cg] =
          make_float4(acc[b][0], acc[b][1], acc[b][2], acc[b][3]);
  }
  __syncthreads();

  {  // epilogue: bias + residual, coalesced out
    const int b = tid >> 5;
    const int colq = (tid & 31) * 4;
    const int cc = slice * 128 + colq;
    const size_t off = ((size_t)b * TT + t) * TD + cc;
    const float4 bias = *(const float4*)(b2 + (size_t)t * TD + cc);
    const float4 xres = *(const float4*)(x + off);
    float4 o;
    float* po = (float*)&o;
    const float* pb = (const float*)&bias;
    const float* px = (const float*)&xres;
#pragma unroll
    for (int k = 0; k < 4; ++k)
      po[k] = red[0][b][colq + k] + red[1][b][colq + k] +
              red[2][b][colq + k] + red[3][b][colq + k] + pb[k] + px[k];
    *(float4*)(out + off) = o;
  }
}

extern "C" void kernel_launch(void* const* d_in, const int* in_sizes, int n_in,
                              void* d_out, int out_size, void* d_ws, size_t ws_size,
                              hipStream_t stream) {
  const float* x     = (const float*)d_in[0];
  const float* gamma = (const float*)d_in[1];
  const float* beta  = (const float*)d_in[2];
  const float* W1    = (const float*)d_in[3];
  const float* b1    = (const float*)d_in[4];
  const float* W2    = (const float*)d_in[5];
  const float* b2    = (const float*)d_in[6];
  float* out = (float*)d_out;

  float* hbuf = (float*)d_ws;   // [T][B][H] = 3 MB

  ff1_kernel<<<TT * 6, 256, 0, stream>>>(x, gamma, beta, W1, b1, hbuf);
  ff2_kernel<<<TT * 6, 256, 0, stream>>>(hbuf, W2, b2, x, out);
}